// Round 1
// baseline (775.764 us; speedup 1.0000x reference)
//
#include <hip/hip_runtime.h>

typedef unsigned char u8;
typedef unsigned int u32;
typedef unsigned long long u64;

#define T_DIM 64
#define B_DIM 8
#define N_DIM 64
#define D_DIM 384
#define H_DIM 8
#define HD 48
#define M_ROWS 32768            // T*B*N = rows of every GEMM
#define CH 196608               // B*N*D = channels per LIF step (also B*T*D)
#define STATS_BLOCKS 256
#define ROWS_PER_BLK 128

// ---------------------------------------------------------------------------
// GEMM (NT): C[m,n] = sum_k X[m,k] * W[n,k];  M=32768, N=K=384, all f32.
// 64x64 tile per block, 256 threads, 4x4 per thread, BK=16, LDS-transposed.
// ---------------------------------------------------------------------------
__global__ __launch_bounds__(256) void gemm_nt(const float* __restrict__ X,
                                               const float* __restrict__ W,
                                               float* __restrict__ C) {
  __shared__ float sX[16][68];  // [k][m], padded row stride 68 (16B-aligned)
  __shared__ float sW[16][68];  // [k][n]
  const int tid = threadIdx.x;
  const int bm = blockIdx.y << 6;
  const int bn = blockIdx.x << 6;
  const int tx = tid & 15;      // n-direction
  const int ty = tid >> 4;      // m-direction
  const int lr = tid >> 2;      // load row 0..63
  const int lk = (tid & 3) << 2;// load k 0,4,8,12

  float acc[4][4] = {};
  const float* xp = X + (size_t)(bm + lr) * D_DIM + lk;
  const float* wp = W + (size_t)(bn + lr) * D_DIM + lk;

  for (int k0 = 0; k0 < D_DIM; k0 += 16) {
    float4 xv = *(const float4*)(xp + k0);
    float4 wv = *(const float4*)(wp + k0);
    __syncthreads();
    sX[lk + 0][lr] = xv.x; sX[lk + 1][lr] = xv.y;
    sX[lk + 2][lr] = xv.z; sX[lk + 3][lr] = xv.w;
    sW[lk + 0][lr] = wv.x; sW[lk + 1][lr] = wv.y;
    sW[lk + 2][lr] = wv.z; sW[lk + 3][lr] = wv.w;
    __syncthreads();
#pragma unroll
    for (int k = 0; k < 16; ++k) {
      float4 a = *(const float4*)&sX[k][ty << 2];
      float4 b = *(const float4*)&sW[k][tx << 2];
      float a4[4] = {a.x, a.y, a.z, a.w};
      float b4[4] = {b.x, b.y, b.z, b.w};
#pragma unroll
      for (int i = 0; i < 4; ++i)
#pragma unroll
        for (int j = 0; j < 4; ++j)
          acc[i][j] = fmaf(a4[i], b4[j], acc[i][j]);
    }
  }
#pragma unroll
  for (int i = 0; i < 4; ++i) {
    float4 o = make_float4(acc[i][0], acc[i][1], acc[i][2], acc[i][3]);
    *(float4*)&C[(size_t)(bm + (ty << 2) + i) * D_DIM + bn + (tx << 2)] = o;
  }
}

// ---------------------------------------------------------------------------
// BN stats: per-channel (D=384) sum & sumsq over 32768 rows, two-stage,
// fixed order, double accumulation (deterministic — no atomics).
// ---------------------------------------------------------------------------
__global__ void bn_stats_partial(const float* __restrict__ Y,
                                 double* __restrict__ part) {
  const int c = threadIdx.x;  // 384 threads
  const size_t r0 = (size_t)blockIdx.x * ROWS_PER_BLK;
  double s = 0.0, q = 0.0;
  for (int r = 0; r < ROWS_PER_BLK; ++r) {
    float v = Y[(r0 + r) * D_DIM + c];
    s += (double)v;
    q += (double)v * (double)v;
  }
  part[((size_t)blockIdx.x * D_DIM + c) * 2 + 0] = s;
  part[((size_t)blockIdx.x * D_DIM + c) * 2 + 1] = q;
}

__global__ void bn_stats_final(const double* __restrict__ part,
                               const float* __restrict__ gamma,
                               const float* __restrict__ beta,
                               float* __restrict__ ss) {
  const int c = threadIdx.x;  // 384 threads, 1 block
  double s = 0.0, q = 0.0;
  for (int b = 0; b < STATS_BLOCKS; ++b) {
    s += part[((size_t)b * D_DIM + c) * 2 + 0];
    q += part[((size_t)b * D_DIM + c) * 2 + 1];
  }
  const double n = (double)M_ROWS;
  const double mean = s / n;
  const double var = q / n - mean * mean;
  const double rstd = 1.0 / sqrt(var + 1e-5);
  const double sc = (double)gamma[c] * rstd;
  ss[c * 2 + 0] = (float)sc;
  ss[c * 2 + 1] = (float)((double)beta[c] - mean * sc);
}

// ---------------------------------------------------------------------------
// LIF scan over leading axis (64 steps, stride CH).
// MODE 0: BN affine then LIF, write u8 spikes (branch q/k/v).
// MODE 1: plain LIF, overwrite Y with f32 spikes (attn_lif).
// MODE 2: BN affine then LIF, overwrite Y with f32 spikes (proj_lif).
// h = v + (x - v)/2 ; s = (h >= 1) ; v = (1-s)*h
// ---------------------------------------------------------------------------
template <int MODE>
__global__ __launch_bounds__(256) void lif_kernel(float* Y,
                                                  const float* __restrict__ ss,
                                                  u8* __restrict__ spikes) {
  const int c = blockIdx.x * 256 + threadIdx.x;  // channel (b,n,dd)
  float scale = 1.0f, shift = 0.0f;
  if (MODE != 1) {
    const int dd = c % D_DIM;
    scale = ss[dd * 2 + 0];
    shift = ss[dd * 2 + 1];
  }
  float v = 0.0f;
  for (int t = 0; t < T_DIM; ++t) {
    const size_t idx = (size_t)t * CH + c;
    float xv = Y[idx];
    if (MODE != 1) xv = xv * scale + shift;
    const float hh = v + (xv - v) * 0.5f;
    const float sp = (hh >= 1.0f) ? 1.0f : 0.0f;
    v = (1.0f - sp) * hh;
    if (MODE == 0)
      spikes[idx] = (u8)sp;
    else
      Y[idx] = sp;
  }
}

// ---------------------------------------------------------------------------
// Attention: block = (x,b,h). Spikes are binary -> pack rows to 48-bit masks,
// S[i][j] = popcount(q_i & k_j) * mask(i,j);  Z[i][d] = sum_j S[i][j]*V[j][d].
// z written in permuted layout (i, b, x, h, d).
// ---------------------------------------------------------------------------
__global__ __launch_bounds__(256) void attn_kernel(const u8* __restrict__ qs,
                                                   const u8* __restrict__ ks,
                                                   const u8* __restrict__ vs,
                                                   float* __restrict__ z) {
  const int gid = blockIdx.x;
  const int h = gid & 7;
  const int b = (gid >> 3) & 7;
  const int x = gid >> 6;
  const int tid = threadIdx.x;

  __shared__ u64 qb[64];
  __shared__ u64 kb[64];
  __shared__ float sS[64][65];
  __shared__ u8 sV[64][48];

  if (tid < 64) {
    const int i = tid;  // Q row: qh[x, b, i, h, :]
    const u32* p = (const u32*)(qs + ((size_t)((x * B_DIM + b) * N_DIM + i)) * D_DIM + h * HD);
    u64 bits = 0;
#pragma unroll
    for (int w = 0; w < 12; ++w) {
      u32 u = p[w];
      u32 nib = (u & 1u) | ((u >> 7) & 2u) | ((u >> 14) & 4u) | ((u >> 21) & 8u);
      bits |= (u64)nib << (w * 4);
    }
    qb[i] = bits;
  } else if (tid < 128) {
    const int j = tid - 64;  // K row: kh[j, b, x, h, :]
    const u32* p = (const u32*)(ks + ((size_t)((j * B_DIM + b) * N_DIM + x)) * D_DIM + h * HD);
    u64 bits = 0;
#pragma unroll
    for (int w = 0; w < 12; ++w) {
      u32 u = p[w];
      u32 nib = (u & 1u) | ((u >> 7) & 2u) | ((u >> 14) & 4u) | ((u >> 21) & 8u);
      bits |= (u64)nib << (w * 4);
    }
    kb[j] = bits;
  } else if (tid < 192) {
    const int j = tid - 128;  // V row: vh[j, b, x, h, :]
    const u32* p = (const u32*)(vs + ((size_t)((j * B_DIM + b) * N_DIM + x)) * D_DIM + h * HD);
    u32* dst = (u32*)&sV[j][0];
#pragma unroll
    for (int w = 0; w < 12; ++w) dst[w] = p[w];
  }
  __syncthreads();

  // S phase: 4096 entries, 16 per thread (fixed i per thread)
  {
    const int i = tid >> 2;
    const u64 qi = qb[i];
#pragma unroll
    for (int r = 0; r < 16; ++r) {
      const int j = ((tid & 3) << 4) + r;
      const int cnt = __popcll(qi & kb[j]);
      int ad = i - j;
      if (ad < 0) ad = -ad;
      sS[i][j] = (float)cnt * (1.0f / (float)(1 + ad));
    }
  }
  __syncthreads();

  // Z phase: 3072 outputs, 12 per thread
  const float kScale = 0.05103103630798287f;  // 384^-0.5
#pragma unroll
  for (int r = 0; r < 12; ++r) {
    const int o = (r << 8) + tid;
    const int i = o / HD;
    const int d = o - i * HD;
    float acc = 0.0f;
#pragma unroll
    for (int j = 0; j < 64; ++j)
      acc = fmaf(sS[i][j], (float)sV[j][d], acc);
    z[((size_t)((i * B_DIM + b) * T_DIM + x)) * D_DIM + h * HD + d] = acc * kScale;
  }
}

// ---------------------------------------------------------------------------
extern "C" void kernel_launch(void* const* d_in, const int* in_sizes, int n_in,
                              void* d_out, int out_size, void* d_ws, size_t ws_size,
                              hipStream_t stream) {
  const float* q  = (const float*)d_in[0];
  const float* kv = (const float*)d_in[1];
  const float* Wq = (const float*)d_in[2];
  const float* gq = (const float*)d_in[3];
  const float* bq = (const float*)d_in[4];
  const float* Wk = (const float*)d_in[5];
  const float* gk = (const float*)d_in[6];
  const float* bk = (const float*)d_in[7];
  const float* Wv = (const float*)d_in[8];
  const float* gv = (const float*)d_in[9];
  const float* bv = (const float*)d_in[10];
  const float* Wp = (const float*)d_in[11];
  const float* gp = (const float*)d_in[12];
  const float* bp = (const float*)d_in[13];
  float* out = (float*)d_out;
  char* ws = (char*)d_ws;

  // workspace layout (bytes)
  float* Ybuf = (float*)(ws + 0);                 // 50,331,648  (reused as z)
  u8* qsb     = (u8*)(ws + 50331648ull);          // 12,582,912
  u8* ksb     = (u8*)(ws + 62914560ull);          // 12,582,912
  u8* vsb     = (u8*)(ws + 75497472ull);          // 12,582,912
  double* part = (double*)(ws + 88080384ull);     //  1,572,864
  float* ss    = (float*)(ws + 89653248ull);      //      3,072

  dim3 gg(6, 512);  // N/64 x M/64

  // --- q branch ---
  gemm_nt<<<gg, 256, 0, stream>>>(q, Wq, Ybuf);
  bn_stats_partial<<<STATS_BLOCKS, D_DIM, 0, stream>>>(Ybuf, part);
  bn_stats_final<<<1, D_DIM, 0, stream>>>(part, gq, bq, ss);
  lif_kernel<0><<<CH / 256, 256, 0, stream>>>(Ybuf, ss, qsb);

  // --- k branch ---
  gemm_nt<<<gg, 256, 0, stream>>>(kv, Wk, Ybuf);
  bn_stats_partial<<<STATS_BLOCKS, D_DIM, 0, stream>>>(Ybuf, part);
  bn_stats_final<<<1, D_DIM, 0, stream>>>(part, gk, bk, ss);
  lif_kernel<0><<<CH / 256, 256, 0, stream>>>(Ybuf, ss, ksb);

  // --- v branch ---
  gemm_nt<<<gg, 256, 0, stream>>>(kv, Wv, Ybuf);
  bn_stats_partial<<<STATS_BLOCKS, D_DIM, 0, stream>>>(Ybuf, part);
  bn_stats_final<<<1, D_DIM, 0, stream>>>(part, gv, bv, ss);
  lif_kernel<0><<<CH / 256, 256, 0, stream>>>(Ybuf, ss, vsb);

  // --- attention (writes z into Ybuf in permuted (i,b,x,h,d) layout) ---
  attn_kernel<<<T_DIM * B_DIM * H_DIM, 256, 0, stream>>>(qsb, ksb, vsb, Ybuf);

  // --- attn_lif (in place, f32 spikes) ---
  lif_kernel<1><<<CH / 256, 256, 0, stream>>>(Ybuf, (const float*)nullptr, (u8*)nullptr);

  // --- proj GEMM -> d_out, BN stats, proj_lif in place ---
  gemm_nt<<<gg, 256, 0, stream>>>(Ybuf, Wp, out);
  bn_stats_partial<<<STATS_BLOCKS, D_DIM, 0, stream>>>(out, part);
  bn_stats_final<<<1, D_DIM, 0, stream>>>(part, gp, bp, ss);
  lif_kernel<2><<<CH / 256, 256, 0, stream>>>(out, ss, (u8*)nullptr);
}